// Round 2
// baseline (939.006 us; speedup 1.0000x reference)
//
#include <hip/hip_runtime.h>
#include <math.h>

constexpr int B  = 4;
constexpr int S  = 12;
constexpr int N  = 20000;
constexpr int HD = 64;
constexpr int E0 = 640000;
constexpr int EL = E0 + N;      // edges + self loops
constexpr int BN = B * N;

// ---------------- CSR build (edges -> per-dst lists) ----------------
__global__ void count_kernel(const int* __restrict__ ei, int* __restrict__ count) {
    int e = blockIdx.x * blockDim.x + threadIdx.x;
    if (e >= EL) return;
    int d = (e < E0) ? ei[E0 + e] : (e - E0);
    atomicAdd(&count[d], 1);
}

// single block 1024 threads: inclusive scan of count -> offsets[1..N], cursor=exclusive
__global__ void scan_kernel(int* __restrict__ cursor, int* __restrict__ offsets) {
    __shared__ int wsum[16];
    int lane = threadIdx.x & 63, wid = threadIdx.x >> 6;
    int carry = 0;
    if (threadIdx.x == 0) offsets[0] = 0;
    for (int base = 0; base < N; base += 1024) {
        int i = base + threadIdx.x;
        int v = (i < N) ? cursor[i] : 0;
        int x = v;
        #pragma unroll
        for (int d = 1; d < 64; d <<= 1) {
            int y = __shfl_up(x, d, 64);
            if (lane >= d) x += y;
        }
        if (lane == 63) wsum[wid] = x;
        __syncthreads();
        int woff = 0;
        for (int w = 0; w < wid; ++w) woff += wsum[w];
        int incl = carry + woff + x;
        if (i < N) { offsets[i + 1] = incl; cursor[i] = incl - v; }
        int total = 0;
        #pragma unroll
        for (int w = 0; w < 16; ++w) total += wsum[w];
        __syncthreads();               // protect wsum before next chunk writes
        carry += total;
    }
}

__global__ void scatter_kernel(const int* __restrict__ ei, int* __restrict__ cursor,
                               int* __restrict__ perm_src, int* __restrict__ perm_dst) {
    int e = blockIdx.x * blockDim.x + threadIdx.x;
    if (e >= EL) return;
    int s, d;
    if (e < E0) { s = ei[e]; d = ei[E0 + e]; }
    else        { s = e - E0; d = s; }
    int pos = atomicAdd(&cursor[d], 1);
    perm_src[pos] = s;
    perm_dst[pos] = d;
}

// ---- conv weight transpose: cwT[(c*3+dt)*64+o] = cw[o*192 + c*3 + dt] ------
__global__ void tw_kernel(const float* __restrict__ cw, float* __restrict__ cwT) {
    int i = blockIdx.x * blockDim.x + threadIdx.x;
    if (i >= HD * HD * 3) return;
    int o = i / (HD * 3), rem = i % (HD * 3), c = rem / 3, dt = rem % 3;
    cwT[(c * 3 + dt) * HD + o] = cw[i];
}

// ------- projection, k-split by blockIdx.y (2 parts of 32) -------------------
__global__ __launch_bounds__(256, 4)
void proj_kernel(const float* __restrict__ x, const float* __restrict__ w,
                 const float* __restrict__ bias, float* __restrict__ out) {
    constexpr int KP = 32;
    int t = blockIdx.x * blockDim.x + threadIdx.x;
    if (t >= BN) return;
    int part = blockIdx.y;             // wave-uniform -> scalar weight loads
    int bb = t / N, n = t - bb * N;
    const float* xp = x + (size_t)bb * S * N + n;
    float xs[S];
    #pragma unroll
    for (int s = 0; s < S; ++s) xs[s] = xp[(size_t)s * N];
    float acc[KP];
    #pragma unroll
    for (int k = 0; k < KP; ++k) acc[k] = bias[part * KP + k];
    #pragma unroll
    for (int s = 0; s < S; ++s) {
        #pragma unroll
        for (int k = 0; k < KP; ++k)
            acc[k] = fmaf(xs[s], w[s * HD + part * KP + k], acc[k]);
    }
    float4* op = (float4*)(out + (size_t)t * HD + part * KP);
    #pragma unroll
    for (int q = 0; q < KP / 4; ++q)
        op[q] = make_float4(acc[4*q], acc[4*q+1], acc[4*q+2], acc[4*q+3]);
}

// ------- xe = h @ w (k-split x4 via blockIdx.y); es/ed per head --------------
template<int H>
__global__ __launch_bounds__(256, 4)
void gemm_attn_kernel(const float* __restrict__ hin, const float* __restrict__ w,
                      const float* __restrict__ asrc, const float* __restrict__ adst,
                      float* __restrict__ xe, float* __restrict__ es, float* __restrict__ ed) {
    constexpr int KP = 16;             // k per part
    int t = blockIdx.x * blockDim.x + threadIdx.x;
    if (t >= BN) return;
    int part = blockIdx.y;             // wave-uniform
    const float4* rp = (const float4*)(hin + (size_t)t * HD);
    float acc[KP];
    #pragma unroll
    for (int k = 0; k < KP; ++k) acc[k] = 0.f;
    for (int c0 = 0; c0 < HD; c0 += 4) {
        float4 v = rp[c0 / 4];
        float r4[4] = {v.x, v.y, v.z, v.w};
        #pragma unroll
        for (int j = 0; j < 4; ++j) {
            #pragma unroll
            for (int k = 0; k < KP; ++k)
                acc[k] = fmaf(r4[j], w[(c0 + j) * HD + part * KP + k], acc[k]);
        }
    }
    float4* op = (float4*)(xe + (size_t)t * HD + part * KP);
    #pragma unroll
    for (int q = 0; q < KP / 4; ++q)
        op[q] = make_float4(acc[4*q], acc[4*q+1], acc[4*q+2], acc[4*q+3]);
    if (H == 8) {
        // C=8: this part's 16 k-values = heads 2*part, 2*part+1, fully local
        float e0 = 0.f, e1 = 0.f, d0 = 0.f, d1 = 0.f;
        #pragma unroll
        for (int kk = 0; kk < 8; ++kk) {
            e0 = fmaf(acc[kk],     asrc[part * KP + kk],     e0);
            e1 = fmaf(acc[kk + 8], asrc[part * KP + kk + 8], e1);
            d0 = fmaf(acc[kk],     adst[part * KP + kk],     d0);
            d1 = fmaf(acc[kk + 8], adst[part * KP + kk + 8], d1);
        }
        es[t * 8 + 2 * part]     = e0;
        es[t * 8 + 2 * part + 1] = e1;
        ed[t * 8 + 2 * part]     = d0;
        ed[t * 8 + 2 * part + 1] = d1;
    } else {
        // H=1: partial dot over this part's k range; reduce via atomics (es/ed pre-zeroed)
        float e = 0.f, d = 0.f;
        #pragma unroll
        for (int kk = 0; kk < KP; ++kk) {
            e = fmaf(acc[kk], asrc[part * KP + kk], e);
            d = fmaf(acc[kk], adst[part * KP + kk], d);
        }
        atomicAdd(&es[t], e);
        atomicAdd(&ed[t], d);
    }
}

// ------- edge-parallel alpha: p = exp(leaky_relu(es[src]+ed[dst])) -----------
template<int H>
__global__ __launch_bounds__(256, 4)
void alpha_kernel(const float* __restrict__ es, const float* __restrict__ ed,
                  const int* __restrict__ perm_src, const int* __restrict__ perm_dst,
                  float* __restrict__ pbuf) {
    int tid = blockIdx.x * blockDim.x + threadIdx.x;
    if (tid >= EL * H) return;
    int bb = blockIdx.y;
    int j = tid / H, h = tid - j * H;  // H power of 2 -> shifts
    int src = perm_src[j], dst = perm_dst[j];
    float e = es[((size_t)bb * N + src) * H + h] + ed[((size_t)bb * N + dst) * H + h];
    e = (e > 0.f) ? e : 0.2f * e;
    pbuf[(size_t)bb * EL * H + tid] = __expf(e);
}

// ------- aggregation with precomputed p: one wave per (batch,node) -----------
template<int H, bool DO_ELU>
__global__ __launch_bounds__(256, 4)
void agg_p_kernel(const float* __restrict__ xe, const float* __restrict__ pbuf,
                  const int* __restrict__ offsets, const int* __restrict__ perm_src,
                  const float* __restrict__ bias, float* __restrict__ hout) {
    constexpr int C = HD / H;
    int wid = blockIdx.x * 4 + (threadIdx.x >> 6);
    if (wid >= BN) return;
    int lane = threadIdx.x & 63;
    int bb = wid / N, node = wid - bb * N;
    int off = offsets[node], end = offsets[node + 1];
    int h = lane / C;
    const float* p_b  = pbuf + (size_t)bb * EL * H;
    const float* xe_b = xe   + (size_t)bb * N * HD;
    float acc = 0.f, ssum = 0.f;
    #pragma unroll 4
    for (int j = off; j < end; ++j) {
        int src = perm_src[j];                       // wave-uniform -> broadcast
        float p = p_b[(size_t)j * H + h];
        ssum += p;
        acc = fmaf(p, xe_b[(size_t)src * HD + lane], acc);  // coalesced 256B gather
    }
    float r = acc / ssum + bias[lane];
    if (DO_ELU) r = (r > 0.f) ? r : expm1f(r);
    hout[(size_t)(bb * N + node) * HD + lane] = r;
}

// ------- fused fallback (round-1 proven path) if ws too small ----------------
template<int H, bool DO_ELU>
__global__ __launch_bounds__(256, 4)
void agg_fused_kernel(const float* __restrict__ xe, const float* __restrict__ es,
                      const float* __restrict__ ed, const int* __restrict__ offsets,
                      const int* __restrict__ perm_src, const float* __restrict__ bias,
                      float* __restrict__ hout) {
    constexpr int C = HD / H;
    int wid = blockIdx.x * 4 + (threadIdx.x >> 6);
    if (wid >= BN) return;
    int lane = threadIdx.x & 63;
    int bb = wid / N, node = wid - bb * N;
    int off = offsets[node], end = offsets[node + 1];
    int h = lane / C;
    const float* es_b = es + (size_t)bb * N * H;
    const float* xe_b = xe + (size_t)bb * N * HD;
    float edv = ed[(size_t)(bb * N + node) * H + h];
    float acc = 0.f, ssum = 0.f;
    #pragma unroll 2
    for (int j = off; j < end; ++j) {
        int src = perm_src[j];
        float e = es_b[src * H + h] + edv;
        e = (e > 0.f) ? e : 0.2f * e;
        float p = __expf(e);
        ssum += p;
        acc = fmaf(p, xe_b[(size_t)src * HD + lane], acc);
    }
    float r = acc / ssum + bias[lane];
    if (DO_ELU) r = (r > 0.f) ? r : expm1f(r);
    hout[(size_t)(bb * N + node) * HD + lane] = r;
}

// ------- conv1d(k=3) + relu + 64->3 projection; LDS-staged node tile ---------
constexpr int CT = 128;                 // nodes per block
__global__ __launch_bounds__(CT, 2)
void conv_out_kernel(const float* __restrict__ h, const float* __restrict__ cwT,
                     const float* __restrict__ cb, const float* __restrict__ ow,
                     const float* __restrict__ ob, float* __restrict__ out) {
    __shared__ float sh[(CT + 2) * 65];          // +1 pad: (row+c)%32 banks
    int bb = blockIdx.y;
    int base = blockIdx.x * CT;
    // stage rows base-1 .. base+CT
    for (int fid = threadIdx.x; fid < (CT + 2) * HD; fid += CT) {
        int row = fid >> 6, c = fid & 63;
        int m = base - 1 + row;
        float v = (m >= 0 && m < N) ? h[((size_t)bb * N + m) * HD + c] : 0.f;
        sh[row * 65 + c] = v;
    }
    __syncthreads();
    int n = base + threadIdx.x;
    if (n >= N) return;
    float acc[HD];
    #pragma unroll
    for (int o = 0; o < HD; ++o) acc[o] = cb[o];          // uniform s_load
    for (int c = 0; c < HD; ++c) {
        float r0 = sh[(threadIdx.x)     * 65 + c];
        float r1 = sh[(threadIdx.x + 1) * 65 + c];
        float r2 = sh[(threadIdx.x + 2) * 65 + c];
        const float* wc = cwT + c * 192;                  // [dt][o], uniform s_loads
        #pragma unroll
        for (int o = 0; o < HD; ++o)
            acc[o] = fmaf(r0, wc[o], fmaf(r1, wc[64 + o], fmaf(r2, wc[128 + o], acc[o])));
    }
    float p0 = ob[0], p1 = ob[1], p2 = ob[2];
    #pragma unroll
    for (int o = 0; o < HD; ++o) {
        float v = fmaxf(acc[o], 0.f);
        p0 = fmaf(v, ow[o * 3 + 0], p0);
        p1 = fmaf(v, ow[o * 3 + 1], p1);
        p2 = fmaf(v, ow[o * 3 + 2], p2);
    }
    out[(size_t)bb * 3 * N + 0 * N + n] = p0;
    out[(size_t)bb * 3 * N + 1 * N + n] = p1;
    out[(size_t)bb * 3 * N + 2 * N + n] = p2;
}

extern "C" void kernel_launch(void* const* d_in, const int* in_sizes, int n_in,
                              void* d_out, int out_size, void* d_ws, size_t ws_size,
                              hipStream_t stream) {
    const float* x      = (const float*)d_in[0];
    const int*   ei     = (const int*)  d_in[1];
    const float* proj_w = (const float*)d_in[2];
    const float* proj_b = (const float*)d_in[3];
    const float* g_w [3] = {(const float*)d_in[4], (const float*)d_in[8],  (const float*)d_in[12]};
    const float* g_as[3] = {(const float*)d_in[5], (const float*)d_in[9],  (const float*)d_in[13]};
    const float* g_ad[3] = {(const float*)d_in[6], (const float*)d_in[10], (const float*)d_in[14]};
    const float* g_b [3] = {(const float*)d_in[7], (const float*)d_in[11], (const float*)d_in[15]};
    const float* conv_w = (const float*)d_in[16];
    const float* conv_b = (const float*)d_in[17];
    const float* out_w  = (const float*)d_in[18];
    const float* out_b  = (const float*)d_in[19];
    float* out = (float*)d_out;

    // workspace layout (fp32 elements)
    float* bufA = (float*)d_ws;                      // BN*HD
    float* bufX = bufA + (size_t)BN * HD;            // BN*HD
    float* es   = bufX + (size_t)BN * HD;            // BN*8 (max H)
    float* ed   = es   + (size_t)BN * 8;             // BN*8
    int* offsets  = (int*)(ed + (size_t)BN * 8);     // N+1
    int* cursor   = offsets + (N + 1);               // N
    int* perm_src = cursor + N;                      // EL
    int* perm_dst = perm_src + EL;                   // EL
    float* cwT  = (float*)(perm_dst + EL);           // 64*64*3
    float* pbuf = cwT + HD * HD * 3;                 // EL*8*B (large)
    size_t need = (size_t)((char*)(pbuf + (size_t)EL * 8 * B) - (char*)d_ws);
    bool use_p = (ws_size >= need);

    const int TB = 256;
    const int gBN = (BN + TB - 1) / TB;
    const int gE  = (EL + TB - 1) / TB;

    // CSR build (edges constant across batches/layers)
    hipMemsetAsync(cursor, 0, N * sizeof(int), stream);
    count_kernel  <<<gE, TB, 0, stream>>>(ei, cursor);
    scan_kernel   <<<1, 1024, 0, stream>>>(cursor, offsets);
    scatter_kernel<<<gE, TB, 0, stream>>>(ei, cursor, perm_src, perm_dst);

    // conv weight transpose
    tw_kernel<<<(HD * HD * 3 + TB - 1) / TB, TB, 0, stream>>>(conv_w, cwT);

    // input projection (k-split x2)
    proj_kernel<<<dim3(gBN, 2), TB, 0, stream>>>(x, proj_w, proj_b, bufA);

    // GAT layers 0,1 (H=8) + ELU
    for (int L = 0; L < 2; ++L) {
        gemm_attn_kernel<8><<<dim3(gBN, 4), TB, 0, stream>>>(bufA, g_w[L], g_as[L], g_ad[L], bufX, es, ed);
        if (use_p) {
            alpha_kernel<8><<<dim3((EL * 8 + TB - 1) / TB, B), TB, 0, stream>>>(es, ed, perm_src, perm_dst, pbuf);
            agg_p_kernel<8, true><<<BN / 4, TB, 0, stream>>>(bufX, pbuf, offsets, perm_src, g_b[L], bufA);
        } else {
            agg_fused_kernel<8, true><<<BN / 4, TB, 0, stream>>>(bufX, es, ed, offsets, perm_src, g_b[L], bufA);
        }
    }

    // GAT layer 2 (H=1), no ELU; es/ed reduced via atomics -> zero first
    hipMemsetAsync(es, 0, BN * sizeof(float), stream);
    hipMemsetAsync(ed, 0, BN * sizeof(float), stream);
    gemm_attn_kernel<1><<<dim3(gBN, 4), TB, 0, stream>>>(bufA, g_w[2], g_as[2], g_ad[2], bufX, es, ed);
    if (use_p) {
        alpha_kernel<1><<<dim3((EL + TB - 1) / TB, B), TB, 0, stream>>>(es, ed, perm_src, perm_dst, pbuf);
        agg_p_kernel<1, false><<<BN / 4, TB, 0, stream>>>(bufX, pbuf, offsets, perm_src, g_b[2], bufA);
    } else {
        agg_fused_kernel<1, false><<<BN / 4, TB, 0, stream>>>(bufX, es, ed, offsets, perm_src, g_b[2], bufA);
    }

    // conv1d(k=3) + relu + final projection, writes [B,3,N]
    conv_out_kernel<<<dim3((N + CT - 1) / CT, B), CT, 0, stream>>>(bufA, cwT, conv_b, out_w, out_b, out);
}

// Round 3
// 685.721 us; speedup vs baseline: 1.3694x; 1.3694x over previous
//
#include <hip/hip_runtime.h>
#include <math.h>

constexpr int B  = 4;
constexpr int S  = 12;
constexpr int N  = 20000;
constexpr int HD = 64;
constexpr int E0 = 640000;
constexpr int EL = E0 + N;      // edges + self loops
constexpr int BN = B * N;

// ---------------- CSR build (edges -> per-dst lists) ----------------
__global__ void count_kernel(const int* __restrict__ ei, int* __restrict__ count) {
    int e = blockIdx.x * blockDim.x + threadIdx.x;
    if (e >= EL) return;
    int d = (e < E0) ? ei[E0 + e] : (e - E0);
    atomicAdd(&count[d], 1);
}

// single block 1024 threads: inclusive scan of count -> offsets[1..N], cursor=exclusive
__global__ void scan_kernel(int* __restrict__ cursor, int* __restrict__ offsets) {
    __shared__ int wsum[16];
    int lane = threadIdx.x & 63, wid = threadIdx.x >> 6;
    int carry = 0;
    if (threadIdx.x == 0) offsets[0] = 0;
    for (int base = 0; base < N; base += 1024) {
        int i = base + threadIdx.x;
        int v = (i < N) ? cursor[i] : 0;
        int x = v;
        #pragma unroll
        for (int d = 1; d < 64; d <<= 1) {
            int y = __shfl_up(x, d, 64);
            if (lane >= d) x += y;
        }
        if (lane == 63) wsum[wid] = x;
        __syncthreads();
        int woff = 0;
        for (int w = 0; w < wid; ++w) woff += wsum[w];
        int incl = carry + woff + x;
        if (i < N) { offsets[i + 1] = incl; cursor[i] = incl - v; }
        int total = 0;
        #pragma unroll
        for (int w = 0; w < 16; ++w) total += wsum[w];
        __syncthreads();               // protect wsum before next chunk writes
        carry += total;
    }
}

__global__ void scatter_kernel(const int* __restrict__ ei, int* __restrict__ cursor,
                               int* __restrict__ perm_src) {
    int e = blockIdx.x * blockDim.x + threadIdx.x;
    if (e >= EL) return;
    int s, d;
    if (e < E0) { s = ei[e]; d = ei[E0 + e]; }
    else        { s = e - E0; d = s; }
    int pos = atomicAdd(&cursor[d], 1);
    perm_src[pos] = s;
}

// ---- conv weight transpose: cwT[(c*3+dt)*64+o] = cw[o*192 + c*3 + dt] ------
__global__ void tw_kernel(const float* __restrict__ cw, float* __restrict__ cwT) {
    int i = blockIdx.x * blockDim.x + threadIdx.x;
    if (i >= HD * HD * 3) return;
    int o = i / (HD * 3), rem = i % (HD * 3), c = rem / 3, dt = rem % 3;
    cwT[(c * 3 + dt) * HD + o] = cw[i];
}

// ------- projection, k-split by blockIdx.y (2 parts of 32) -------------------
__global__ __launch_bounds__(256, 4)
void proj_kernel(const float* __restrict__ x, const float* __restrict__ w,
                 const float* __restrict__ bias, float* __restrict__ out) {
    constexpr int KP = 32;
    int t = blockIdx.x * blockDim.x + threadIdx.x;
    if (t >= BN) return;
    int part = blockIdx.y;             // wave-uniform -> scalar weight loads
    int bb = t / N, n = t - bb * N;
    const float* xp = x + (size_t)bb * S * N + n;
    float xs[S];
    #pragma unroll
    for (int s = 0; s < S; ++s) xs[s] = xp[(size_t)s * N];
    float acc[KP];
    #pragma unroll
    for (int k = 0; k < KP; ++k) acc[k] = bias[part * KP + k];
    #pragma unroll
    for (int s = 0; s < S; ++s) {
        #pragma unroll
        for (int k = 0; k < KP; ++k)
            acc[k] = fmaf(xs[s], w[s * HD + part * KP + k], acc[k]);
    }
    float4* op = (float4*)(out + (size_t)t * HD + part * KP);
    #pragma unroll
    for (int q = 0; q < KP / 4; ++q)
        op[q] = make_float4(acc[4*q], acc[4*q+1], acc[4*q+2], acc[4*q+3]);
}

// ------- xe = h @ w ; es/ed per head. LDS-staged rows, coalesced in/out ------
constexpr int GR = 128;                 // rows (nodes) per block
template<int H>
__global__ __launch_bounds__(GR, 2)
void gemm_attn_kernel(const float* __restrict__ hin, const float* __restrict__ w,
                      const float* __restrict__ asrc, const float* __restrict__ adst,
                      float* __restrict__ xe, float* __restrict__ es, float* __restrict__ ed) {
    __shared__ float sh[GR * 65];       // +1 pad: (row+c)%32 banks, 2-way free
    int base = blockIdx.x * GR;         // BN = 625*128 exact
    // stage: coalesced float4 loads of GR rows
    const float4* gin = (const float4*)(hin + (size_t)base * HD);
    for (int i = threadIdx.x; i < GR * (HD / 4); i += GR) {
        float4 v = gin[i];
        int row = i >> 4, q = i & 15;
        sh[row * 65 + 4 * q + 0] = v.x;
        sh[row * 65 + 4 * q + 1] = v.y;
        sh[row * 65 + 4 * q + 2] = v.z;
        sh[row * 65 + 4 * q + 3] = v.w;
    }
    __syncthreads();
    int t = base + threadIdx.x;         // this thread's row
    float acc[HD];
    #pragma unroll
    for (int k = 0; k < HD; ++k) acc[k] = 0.f;
    #pragma unroll 1
    for (int c0 = 0; c0 < HD; c0 += 8) {
        float r8[8];
        #pragma unroll
        for (int j = 0; j < 8; ++j) r8[j] = sh[threadIdx.x * 65 + c0 + j];
        #pragma unroll
        for (int j = 0; j < 8; ++j) {
            #pragma unroll
            for (int k = 0; k < HD; ++k)
                acc[k] = fmaf(r8[j], w[(c0 + j) * HD + k], acc[k]);  // uniform -> s_load
        }
    }
    // attention logits (k = h*C + c matches [H,C] flatten)
    constexpr int C = HD / H;
    float esa[H], eda[H];
    #pragma unroll
    for (int h = 0; h < H; ++h) { esa[h] = 0.f; eda[h] = 0.f; }
    #pragma unroll
    for (int k = 0; k < HD; ++k) {
        esa[k / C] = fmaf(acc[k], asrc[k], esa[k / C]);
        eda[k / C] = fmaf(acc[k], adst[k], eda[k / C]);
    }
    #pragma unroll
    for (int h = 0; h < H; ++h) { es[t * H + h] = esa[h]; ed[t * H + h] = eda[h]; }
    // write xe back through LDS so global stores are coalesced
    __syncthreads();                    // all compute reads of sh done
    #pragma unroll
    for (int k = 0; k < HD; ++k) sh[threadIdx.x * 65 + k] = acc[k];
    __syncthreads();
    float4* gout = (float4*)(xe + (size_t)base * HD);
    for (int i = threadIdx.x; i < GR * (HD / 4); i += GR) {
        int row = i >> 4, q = i & 15;
        gout[i] = make_float4(sh[row * 65 + 4*q], sh[row * 65 + 4*q + 1],
                              sh[row * 65 + 4*q + 2], sh[row * 65 + 4*q + 3]);
    }
}

// ------- fused aggregation: one wave per (batch,node); lane = channel --------
// out[i,c] = (sum_j p_j * xe[src_j, c]) / (sum_j p_j) + bias[c]
// p_j = __expf(leaky_relu(es[src_j,h] + ed[i,h])), h = c / C
// int-only addressing + __expf: ~11 VALU/edge (vs ~67 with libm expf + size_t)
template<int H, bool DO_ELU>
__global__ __launch_bounds__(256, 4)
void agg_kernel(const float* __restrict__ xe, const float* __restrict__ es,
                const float* __restrict__ ed, const int* __restrict__ offsets,
                const int* __restrict__ perm_src, const float* __restrict__ bias,
                float* __restrict__ hout) {
    constexpr int C = HD / H;
    int wid = blockIdx.x * 4 + (threadIdx.x >> 6);
    if (wid >= BN) return;
    int lane = threadIdx.x & 63;
    int bb = wid / N, node = wid - bb * N;
    int off = offsets[node], end = offsets[node + 1];
    int h = (H == 1) ? 0 : (lane / C);
    const float* es_b = es + bb * (N * H);
    const float* xe_b = xe + bb * (N * HD);
    float edv = ed[(bb * N + node) * H + h];
    float acc0 = 0.f, acc1 = 0.f, s0 = 0.f, s1 = 0.f;
    int j = off;
    #pragma unroll 2
    for (; j + 1 < end; j += 2) {
        int sa = perm_src[j];
        int sb = perm_src[j + 1];
        float ea = es_b[sa * H + h] + edv;
        float eb = es_b[sb * H + h] + edv;
        ea = fmaxf(ea, 0.2f * ea);               // leaky_relu(0.2)
        eb = fmaxf(eb, 0.2f * eb);
        float pa = __expf(ea);
        float pb = __expf(eb);
        s0 += pa; s1 += pb;
        acc0 = fmaf(pa, xe_b[sa * HD + lane], acc0);
        acc1 = fmaf(pb, xe_b[sb * HD + lane], acc1);
    }
    if (j < end) {
        int sa = perm_src[j];
        float ea = es_b[sa * H + h] + edv;
        ea = fmaxf(ea, 0.2f * ea);
        float pa = __expf(ea);
        s0 += pa;
        acc0 = fmaf(pa, xe_b[sa * HD + lane], acc0);
    }
    float r = (acc0 + acc1) / (s0 + s1) + bias[lane];
    if (DO_ELU) r = (r > 0.f) ? r : expm1f(r);
    hout[(bb * N + node) * HD + lane] = r;
}

// ------- conv1d(k=3) + relu + 64->3 projection; LDS-staged node tile ---------
constexpr int CT = 128;                 // nodes per block
__global__ __launch_bounds__(CT, 2)
void conv_out_kernel(const float* __restrict__ h, const float* __restrict__ cwT,
                     const float* __restrict__ cb, const float* __restrict__ ow,
                     const float* __restrict__ ob, float* __restrict__ out) {
    __shared__ float sh[(CT + 2) * 65];          // +1 pad
    int bb = blockIdx.y;
    int base = blockIdx.x * CT;
    // stage rows base-1 .. base+CT
    for (int fid = threadIdx.x; fid < (CT + 2) * HD; fid += CT) {
        int row = fid >> 6, c = fid & 63;
        int m = base - 1 + row;
        float v = (m >= 0 && m < N) ? h[((size_t)bb * N + m) * HD + c] : 0.f;
        sh[row * 65 + c] = v;
    }
    __syncthreads();
    int n = base + threadIdx.x;
    if (n >= N) return;
    float acc[HD];
    #pragma unroll
    for (int o = 0; o < HD; ++o) acc[o] = cb[o];          // uniform s_load
    for (int c = 0; c < HD; ++c) {
        float r0 = sh[(threadIdx.x)     * 65 + c];
        float r1 = sh[(threadIdx.x + 1) * 65 + c];
        float r2 = sh[(threadIdx.x + 2) * 65 + c];
        const float* wc = cwT + c * 192;                  // [dt][o], uniform s_loads
        #pragma unroll
        for (int o = 0; o < HD; ++o)
            acc[o] = fmaf(r0, wc[o], fmaf(r1, wc[64 + o], fmaf(r2, wc[128 + o], acc[o])));
    }
    float p0 = ob[0], p1 = ob[1], p2 = ob[2];
    #pragma unroll
    for (int o = 0; o < HD; ++o) {
        float v = fmaxf(acc[o], 0.f);
        p0 = fmaf(v, ow[o * 3 + 0], p0);
        p1 = fmaf(v, ow[o * 3 + 1], p1);
        p2 = fmaf(v, ow[o * 3 + 2], p2);
    }
    out[(size_t)bb * 3 * N + 0 * N + n] = p0;
    out[(size_t)bb * 3 * N + 1 * N + n] = p1;
    out[(size_t)bb * 3 * N + 2 * N + n] = p2;
}

extern "C" void kernel_launch(void* const* d_in, const int* in_sizes, int n_in,
                              void* d_out, int out_size, void* d_ws, size_t ws_size,
                              hipStream_t stream) {
    const float* x      = (const float*)d_in[0];
    const int*   ei     = (const int*)  d_in[1];
    const float* proj_w = (const float*)d_in[2];
    const float* proj_b = (const float*)d_in[3];
    const float* g_w [3] = {(const float*)d_in[4], (const float*)d_in[8],  (const float*)d_in[12]};
    const float* g_as[3] = {(const float*)d_in[5], (const float*)d_in[9],  (const float*)d_in[13]};
    const float* g_ad[3] = {(const float*)d_in[6], (const float*)d_in[10], (const float*)d_in[14]};
    const float* g_b [3] = {(const float*)d_in[7], (const float*)d_in[11], (const float*)d_in[15]};
    const float* conv_w = (const float*)d_in[16];
    const float* conv_b = (const float*)d_in[17];
    const float* out_w  = (const float*)d_in[18];
    const float* out_b  = (const float*)d_in[19];
    float* out = (float*)d_out;

    // workspace layout (fp32 elements)
    float* bufA = (float*)d_ws;                      // BN*HD
    float* bufX = bufA + (size_t)BN * HD;            // BN*HD
    float* es   = bufX + (size_t)BN * HD;            // BN*8 (max H)
    float* ed   = es   + (size_t)BN * 8;             // BN*8
    int* offsets  = (int*)(ed + (size_t)BN * 8);     // N+1
    int* cursor   = offsets + (N + 1);               // N
    int* perm_src = cursor + N;                      // EL
    float* cwT  = (float*)(perm_src + EL);           // 64*64*3

    const int TB = 256;
    const int gBN = (BN + TB - 1) / TB;
    const int gE  = (EL + TB - 1) / TB;

    // CSR build (edges constant across batches/layers)
    hipMemsetAsync(cursor, 0, N * sizeof(int), stream);
    count_kernel  <<<gE, TB, 0, stream>>>(ei, cursor);
    scan_kernel   <<<1, 1024, 0, stream>>>(cursor, offsets);
    scatter_kernel<<<gE, TB, 0, stream>>>(ei, cursor, perm_src);

    // conv weight transpose
    tw_kernel<<<(HD * HD * 3 + TB - 1) / TB, TB, 0, stream>>>(conv_w, cwT);

    // input projection (k-split x2)
    proj_kernel<<<dim3(gBN, 2), TB, 0, stream>>>(x, proj_w, proj_b, bufA);

    // GAT layers 0,1 (H=8) + ELU
    for (int L = 0; L < 2; ++L) {
        gemm_attn_kernel<8><<<BN / GR, GR, 0, stream>>>(bufA, g_w[L], g_as[L], g_ad[L], bufX, es, ed);
        agg_kernel<8, true><<<BN / 4, TB, 0, stream>>>(bufX, es, ed, offsets, perm_src, g_b[L], bufA);
    }

    // GAT layer 2 (H=1), no ELU
    gemm_attn_kernel<1><<<BN / GR, GR, 0, stream>>>(bufA, g_w[2], g_as[2], g_ad[2], bufX, es, ed);
    agg_kernel<1, false><<<BN / 4, TB, 0, stream>>>(bufX, es, ed, offsets, perm_src, g_b[2], bufA);

    // conv1d(k=3) + relu + final projection, writes [B,3,N]
    conv_out_kernel<<<dim3((N + CT - 1) / CT, B), CT, 0, stream>>>(bufA, cwT, conv_b, out_w, out_b, out);
}

// Round 4
// 665.881 us; speedup vs baseline: 1.4102x; 1.0298x over previous
//
#include <hip/hip_runtime.h>
#include <math.h>

constexpr int B  = 4;
constexpr int S  = 12;
constexpr int N  = 20000;
constexpr int HD = 64;
constexpr int E0 = 640000;
constexpr int EL = E0 + N;      // edges + self loops
constexpr int BN = B * N;

// ---------------- CSR build (edges -> per-dst lists) ----------------
__global__ void count_kernel(const int* __restrict__ ei, int* __restrict__ count) {
    int e = blockIdx.x * blockDim.x + threadIdx.x;
    if (e >= EL) return;
    int d = (e < E0) ? ei[E0 + e] : (e - E0);
    atomicAdd(&count[d], 1);
}

// single block 1024 threads: inclusive scan of count -> offsets[1..N], cursor=exclusive
__global__ void scan_kernel(int* __restrict__ cursor, int* __restrict__ offsets) {
    __shared__ int wsum[16];
    int lane = threadIdx.x & 63, wid = threadIdx.x >> 6;
    int carry = 0;
    if (threadIdx.x == 0) offsets[0] = 0;
    for (int base = 0; base < N; base += 1024) {
        int i = base + threadIdx.x;
        int v = (i < N) ? cursor[i] : 0;
        int x = v;
        #pragma unroll
        for (int d = 1; d < 64; d <<= 1) {
            int y = __shfl_up(x, d, 64);
            if (lane >= d) x += y;
        }
        if (lane == 63) wsum[wid] = x;
        __syncthreads();
        int woff = 0;
        for (int w = 0; w < wid; ++w) woff += wsum[w];
        int incl = carry + woff + x;
        if (i < N) { offsets[i + 1] = incl; cursor[i] = incl - v; }
        int total = 0;
        #pragma unroll
        for (int w = 0; w < 16; ++w) total += wsum[w];
        __syncthreads();               // protect wsum before next chunk writes
        carry += total;
    }
}

__global__ void scatter_kernel(const int* __restrict__ ei, int* __restrict__ cursor,
                               int* __restrict__ perm_src) {
    int e = blockIdx.x * blockDim.x + threadIdx.x;
    if (e >= EL) return;
    int s, d;
    if (e < E0) { s = ei[e]; d = ei[E0 + e]; }
    else        { s = e - E0; d = s; }
    int pos = atomicAdd(&cursor[d], 1);
    perm_src[pos] = s;
}

// ---- conv weight transpose: cwT[(c*3+dt)*64+o] = cw[o*192 + c*3 + dt] ------
__global__ void tw_kernel(const float* __restrict__ cw, float* __restrict__ cwT) {
    int i = blockIdx.x * blockDim.x + threadIdx.x;
    if (i >= HD * HD * 3) return;
    int o = i / (HD * 3), rem = i % (HD * 3), c = rem / 3, dt = rem % 3;
    cwT[(c * 3 + dt) * HD + o] = cw[i];
}

// ------- projection, k-split by blockIdx.y (2 parts of 32) -------------------
__global__ __launch_bounds__(256, 4)
void proj_kernel(const float* __restrict__ x, const float* __restrict__ w,
                 const float* __restrict__ bias, float* __restrict__ out) {
    constexpr int KP = 32;
    int t = blockIdx.x * blockDim.x + threadIdx.x;
    if (t >= BN) return;
    int part = blockIdx.y;             // wave-uniform -> scalar weight loads
    int bb = t / N, n = t - bb * N;
    const float* xp = x + (size_t)bb * S * N + n;
    float xs[S];
    #pragma unroll
    for (int s = 0; s < S; ++s) xs[s] = xp[(size_t)s * N];
    float acc[KP];
    #pragma unroll
    for (int k = 0; k < KP; ++k) acc[k] = bias[part * KP + k];
    #pragma unroll
    for (int s = 0; s < S; ++s) {
        #pragma unroll
        for (int k = 0; k < KP; ++k)
            acc[k] = fmaf(xs[s], w[s * HD + part * KP + k], acc[k]);
    }
    float4* op = (float4*)(out + (size_t)t * HD + part * KP);
    #pragma unroll
    for (int q = 0; q < KP / 4; ++q)
        op[q] = make_float4(acc[4*q], acc[4*q+1], acc[4*q+2], acc[4*q+3]);
}

// ------- xe = h @ w ; es/ed per head. LDS-staged rows, coalesced in/out ------
constexpr int GR = 128;                 // rows (nodes) per block
template<int H>
__global__ __launch_bounds__(GR, 2)
void gemm_attn_kernel(const float* __restrict__ hin, const float* __restrict__ w,
                      const float* __restrict__ asrc, const float* __restrict__ adst,
                      float* __restrict__ xe, float* __restrict__ es, float* __restrict__ ed) {
    __shared__ float sh[GR * 65];       // +1 pad: (row+c)%32 banks, 2-way free
    int base = blockIdx.x * GR;         // BN = 625*128 exact
    // stage: coalesced float4 loads of GR rows
    const float4* gin = (const float4*)(hin + (size_t)base * HD);
    for (int i = threadIdx.x; i < GR * (HD / 4); i += GR) {
        float4 v = gin[i];
        int row = i >> 4, q = i & 15;
        sh[row * 65 + 4 * q + 0] = v.x;
        sh[row * 65 + 4 * q + 1] = v.y;
        sh[row * 65 + 4 * q + 2] = v.z;
        sh[row * 65 + 4 * q + 3] = v.w;
    }
    __syncthreads();
    int t = base + threadIdx.x;         // this thread's row
    float acc[HD];
    #pragma unroll
    for (int k = 0; k < HD; ++k) acc[k] = 0.f;
    #pragma unroll 1
    for (int c0 = 0; c0 < HD; c0 += 8) {
        float r8[8];
        #pragma unroll
        for (int j = 0; j < 8; ++j) r8[j] = sh[threadIdx.x * 65 + c0 + j];
        #pragma unroll
        for (int j = 0; j < 8; ++j) {
            #pragma unroll
            for (int k = 0; k < HD; ++k)
                acc[k] = fmaf(r8[j], w[(c0 + j) * HD + k], acc[k]);  // uniform -> s_load
        }
    }
    // attention logits (k = h*C + c matches [H,C] flatten)
    constexpr int C = HD / H;
    float esa[H], eda[H];
    #pragma unroll
    for (int h = 0; h < H; ++h) { esa[h] = 0.f; eda[h] = 0.f; }
    #pragma unroll
    for (int k = 0; k < HD; ++k) {
        esa[k / C] = fmaf(acc[k], asrc[k], esa[k / C]);
        eda[k / C] = fmaf(acc[k], adst[k], eda[k / C]);
    }
    #pragma unroll
    for (int h = 0; h < H; ++h) { es[t * H + h] = esa[h]; ed[t * H + h] = eda[h]; }
    // write xe back through LDS so global stores are coalesced
    __syncthreads();                    // all compute reads of sh done
    #pragma unroll
    for (int k = 0; k < HD; ++k) sh[threadIdx.x * 65 + k] = acc[k];
    __syncthreads();
    float4* gout = (float4*)(xe + (size_t)base * HD);
    for (int i = threadIdx.x; i < GR * (HD / 4); i += GR) {
        int row = i >> 4, q = i & 15;
        gout[i] = make_float4(sh[row * 65 + 4*q], sh[row * 65 + 4*q + 1],
                              sh[row * 65 + 4*q + 2], sh[row * 65 + 4*q + 3]);
    }
}

// ------- fused aggregation: one wave per (batch,node) ------------------------
// Wave layout: 4 groups x 16 lanes. group = lane>>4 owns edge j=jb+group;
// lane (c4 = lane&15) owns channels 4*c4..4*c4+3 (float4). One v_exp serves
// 4 edges; per-edge VALU ~4.5 vs ~14 in the 1-edge/iter version.
template<int H, bool DO_ELU>
__global__ __launch_bounds__(256, 4)
void agg_kernel(const float* __restrict__ xe, const float* __restrict__ es,
                const float* __restrict__ ed, const int* __restrict__ offsets,
                const int* __restrict__ perm_src, const float* __restrict__ bias,
                float* __restrict__ hout) {
    int wid = blockIdx.x * 4 + (threadIdx.x >> 6);
    if (wid >= BN) return;
    int lane  = threadIdx.x & 63;
    int group = lane >> 4;
    int c4    = lane & 15;
    int bb = wid / N, node = wid - bb * N;
    int off = offsets[node], end = offsets[node + 1];
    int h = (H == 8) ? (c4 >> 1) : 0;        // channels 4*c4..+3 lie in one head
    const float*  es_b = es + bb * (N * H);
    const float4* xe4  = (const float4*)(xe + bb * (N * HD));
    float edv = ed[(bb * N + node) * H + h];
    float4 acc = {0.f, 0.f, 0.f, 0.f};
    float ssum = 0.f;
    for (int jb = off; jb < end; jb += 4) {
        int j = jb + group;
        bool valid = (j < end);
        int src = perm_src[valid ? j : (end - 1)];   // >=1 edge (self loop)
        float e = es_b[src * H + h] + edv;
        e = fmaxf(e, 0.2f * e);                      // leaky_relu(0.2)
        float p = valid ? __expf(e) : 0.f;
        ssum += p;
        float4 xv = xe4[src * 16 + c4];              // 256B/group, 4 rows in flight
        acc.x = fmaf(p, xv.x, acc.x);
        acc.y = fmaf(p, xv.y, acc.y);
        acc.z = fmaf(p, xv.z, acc.z);
        acc.w = fmaf(p, xv.w, acc.w);
    }
    // reduce across the 4 groups (lane bits 4,5)
    #pragma unroll
    for (int m = 16; m < 64; m <<= 1) {
        acc.x += __shfl_xor(acc.x, m, 64);
        acc.y += __shfl_xor(acc.y, m, 64);
        acc.z += __shfl_xor(acc.z, m, 64);
        acc.w += __shfl_xor(acc.w, m, 64);
        ssum  += __shfl_xor(ssum,  m, 64);
    }
    if (lane < 16) {
        float inv = 1.f / ssum;
        const float4* b4 = (const float4*)bias;
        float4 bv = b4[c4];
        float4 r;
        r.x = acc.x * inv + bv.x;
        r.y = acc.y * inv + bv.y;
        r.z = acc.z * inv + bv.z;
        r.w = acc.w * inv + bv.w;
        if (DO_ELU) {
            r.x = (r.x > 0.f) ? r.x : expm1f(r.x);
            r.y = (r.y > 0.f) ? r.y : expm1f(r.y);
            r.z = (r.z > 0.f) ? r.z : expm1f(r.z);
            r.w = (r.w > 0.f) ? r.w : expm1f(r.w);
        }
        ((float4*)hout)[(bb * N + node) * 16 + c4] = r;
    }
}

// ------- conv1d(k=3) + relu + 64->3 projection; LDS-staged node tile ---------
constexpr int CT = 128;                 // nodes per block
__global__ __launch_bounds__(CT, 2)
void conv_out_kernel(const float* __restrict__ h, const float* __restrict__ cwT,
                     const float* __restrict__ cb, const float* __restrict__ ow,
                     const float* __restrict__ ob, float* __restrict__ out) {
    __shared__ float sh[(CT + 2) * 65];          // +1 pad
    int bb = blockIdx.y;
    int base = blockIdx.x * CT;
    // stage rows base-1 .. base+CT
    for (int fid = threadIdx.x; fid < (CT + 2) * HD; fid += CT) {
        int row = fid >> 6, c = fid & 63;
        int m = base - 1 + row;
        float v = (m >= 0 && m < N) ? h[((size_t)bb * N + m) * HD + c] : 0.f;
        sh[row * 65 + c] = v;
    }
    __syncthreads();
    int n = base + threadIdx.x;
    if (n >= N) return;
    float acc[HD];
    #pragma unroll
    for (int o = 0; o < HD; ++o) acc[o] = cb[o];          // uniform s_load
    for (int c = 0; c < HD; ++c) {
        float r0 = sh[(threadIdx.x)     * 65 + c];
        float r1 = sh[(threadIdx.x + 1) * 65 + c];
        float r2 = sh[(threadIdx.x + 2) * 65 + c];
        const float* wc = cwT + c * 192;                  // [dt][o], uniform s_loads
        #pragma unroll
        for (int o = 0; o < HD; ++o)
            acc[o] = fmaf(r0, wc[o], fmaf(r1, wc[64 + o], fmaf(r2, wc[128 + o], acc[o])));
    }
    float p0 = ob[0], p1 = ob[1], p2 = ob[2];
    #pragma unroll
    for (int o = 0; o < HD; ++o) {
        float v = fmaxf(acc[o], 0.f);
        p0 = fmaf(v, ow[o * 3 + 0], p0);
        p1 = fmaf(v, ow[o * 3 + 1], p1);
        p2 = fmaf(v, ow[o * 3 + 2], p2);
    }
    out[(size_t)bb * 3 * N + 0 * N + n] = p0;
    out[(size_t)bb * 3 * N + 1 * N + n] = p1;
    out[(size_t)bb * 3 * N + 2 * N + n] = p2;
}

extern "C" void kernel_launch(void* const* d_in, const int* in_sizes, int n_in,
                              void* d_out, int out_size, void* d_ws, size_t ws_size,
                              hipStream_t stream) {
    const float* x      = (const float*)d_in[0];
    const int*   ei     = (const int*)  d_in[1];
    const float* proj_w = (const float*)d_in[2];
    const float* proj_b = (const float*)d_in[3];
    const float* g_w [3] = {(const float*)d_in[4], (const float*)d_in[8],  (const float*)d_in[12]};
    const float* g_as[3] = {(const float*)d_in[5], (const float*)d_in[9],  (const float*)d_in[13]};
    const float* g_ad[3] = {(const float*)d_in[6], (const float*)d_in[10], (const float*)d_in[14]};
    const float* g_b [3] = {(const float*)d_in[7], (const float*)d_in[11], (const float*)d_in[15]};
    const float* conv_w = (const float*)d_in[16];
    const float* conv_b = (const float*)d_in[17];
    const float* out_w  = (const float*)d_in[18];
    const float* out_b  = (const float*)d_in[19];
    float* out = (float*)d_out;

    // workspace layout (fp32 elements)
    float* bufA = (float*)d_ws;                      // BN*HD
    float* bufX = bufA + (size_t)BN * HD;            // BN*HD
    float* es   = bufX + (size_t)BN * HD;            // BN*8 (max H)
    float* ed   = es   + (size_t)BN * 8;             // BN*8
    int* offsets  = (int*)(ed + (size_t)BN * 8);     // N+1
    int* cursor   = offsets + (N + 1);               // N
    int* perm_src = cursor + N;                      // EL
    float* cwT  = (float*)(perm_src + EL);           // 64*64*3

    const int TB = 256;
    const int gBN = (BN + TB - 1) / TB;
    const int gE  = (EL + TB - 1) / TB;

    // CSR build (edges constant across batches/layers)
    hipMemsetAsync(cursor, 0, N * sizeof(int), stream);
    count_kernel  <<<gE, TB, 0, stream>>>(ei, cursor);
    scan_kernel   <<<1, 1024, 0, stream>>>(cursor, offsets);
    scatter_kernel<<<gE, TB, 0, stream>>>(ei, cursor, perm_src);

    // conv weight transpose
    tw_kernel<<<(HD * HD * 3 + TB - 1) / TB, TB, 0, stream>>>(conv_w, cwT);

    // input projection (k-split x2)
    proj_kernel<<<dim3(gBN, 2), TB, 0, stream>>>(x, proj_w, proj_b, bufA);

    // GAT layers 0,1 (H=8) + ELU
    for (int L = 0; L < 2; ++L) {
        gemm_attn_kernel<8><<<BN / GR, GR, 0, stream>>>(bufA, g_w[L], g_as[L], g_ad[L], bufX, es, ed);
        agg_kernel<8, true><<<BN / 4, TB, 0, stream>>>(bufX, es, ed, offsets, perm_src, g_b[L], bufA);
    }

    // GAT layer 2 (H=1), no ELU
    gemm_attn_kernel<1><<<BN / GR, GR, 0, stream>>>(bufA, g_w[2], g_as[2], g_ad[2], bufX, es, ed);
    agg_kernel<1, false><<<BN / 4, TB, 0, stream>>>(bufX, es, ed, offsets, perm_src, g_b[2], bufA);

    // conv1d(k=3) + relu + final projection, writes [B,3,N]
    conv_out_kernel<<<dim3((N + CT - 1) / CT, B), CT, 0, stream>>>(bufA, cwT, conv_b, out_w, out_b, out);
}

// Round 5
// 560.906 us; speedup vs baseline: 1.6741x; 1.1872x over previous
//
#include <hip/hip_runtime.h>
#include <math.h>

constexpr int B  = 4;
constexpr int S  = 12;
constexpr int N  = 20000;
constexpr int HD = 64;
constexpr int E0 = 640000;
constexpr int EL = E0 + N;      // edges + self loops
constexpr int BN = B * N;
constexpr int CAP = 128;        // padded CSR bucket capacity (deg: mean 32, sd 5.7)

// ---------------- padded-bucket CSR build: one kernel, no scan ---------------
__global__ void scatter_kernel(const int* __restrict__ ei, int* __restrict__ cnt,
                               int* __restrict__ perm) {
    int e = blockIdx.x * blockDim.x + threadIdx.x;
    if (e >= EL) return;
    int s, d;
    if (e < E0) { s = ei[e]; d = ei[E0 + e]; }
    else        { s = e - E0; d = s; }
    int pos = atomicAdd(&cnt[d], 1) & (CAP - 1);   // mask: can't corrupt neighbors
    perm[d * CAP + pos] = s;
}

// ---- conv weight transpose: cwT[(c*3+dt)*64+o] = cw[o*192 + c*3 + dt] ------
__global__ void tw_kernel(const float* __restrict__ cw, float* __restrict__ cwT) {
    int i = blockIdx.x * blockDim.x + threadIdx.x;
    if (i >= HD * HD * 3) return;
    int o = i / (HD * 3), rem = i % (HD * 3), c = rem / 3, dt = rem % 3;
    cwT[(c * 3 + dt) * HD + o] = cw[i];
}

constexpr int GR = 128;                 // rows (nodes) per block

// ------- fused: h = x@pw+pb (registers), xe = h@w, es/ed. Layer 0 only. ------
__global__ __launch_bounds__(GR, 2)
void fused0_kernel(const float* __restrict__ x, const float* __restrict__ pw,
                   const float* __restrict__ pb, const float* __restrict__ w,
                   const float* __restrict__ asrc, const float* __restrict__ adst,
                   float* __restrict__ xe, float* __restrict__ es, float* __restrict__ ed) {
    __shared__ float sh[GR * 65];
    int base = blockIdx.x * GR;         // BN = 625*128 exact
    int t = base + threadIdx.x;
    int bb = t / N, n = t - bb * N;
    float h[HD];
    {
        float xs[S];
        #pragma unroll
        for (int s = 0; s < S; ++s) xs[s] = x[(bb * S + s) * N + n];  // coalesced
        #pragma unroll
        for (int k = 0; k < HD; ++k) h[k] = pb[k];
        #pragma unroll
        for (int s = 0; s < S; ++s) {
            #pragma unroll
            for (int k = 0; k < HD; ++k)
                h[k] = fmaf(xs[s], pw[s * HD + k], h[k]);             // uniform s_load
        }
    }
    float acc[HD];
    #pragma unroll
    for (int k = 0; k < HD; ++k) acc[k] = 0.f;
    #pragma unroll 1
    for (int c0 = 0; c0 < HD; c0 += 8) {
        #pragma unroll
        for (int j = 0; j < 8; ++j) {
            #pragma unroll
            for (int k = 0; k < HD; ++k)
                acc[k] = fmaf(h[c0 + j], w[(c0 + j) * HD + k], acc[k]);
        }
    }
    // attention logits, H=8, C=8: head = k>>3
    float esa[8], eda[8];
    #pragma unroll
    for (int hh = 0; hh < 8; ++hh) { esa[hh] = 0.f; eda[hh] = 0.f; }
    #pragma unroll
    for (int k = 0; k < HD; ++k) {
        esa[k >> 3] = fmaf(acc[k], asrc[k], esa[k >> 3]);
        eda[k >> 3] = fmaf(acc[k], adst[k], eda[k >> 3]);
    }
    #pragma unroll
    for (int hh = 0; hh < 8; ++hh) { es[t * 8 + hh] = esa[hh]; ed[t * 8 + hh] = eda[hh]; }
    // coalesced xe store through LDS
    #pragma unroll
    for (int k = 0; k < HD; ++k) sh[threadIdx.x * 65 + k] = acc[k];
    __syncthreads();
    float4* gout = (float4*)(xe + (size_t)base * HD);
    for (int i = threadIdx.x; i < GR * (HD / 4); i += GR) {
        int row = i >> 4, q = i & 15;
        gout[i] = make_float4(sh[row * 65 + 4*q], sh[row * 65 + 4*q + 1],
                              sh[row * 65 + 4*q + 2], sh[row * 65 + 4*q + 3]);
    }
}

// ------- xe = h @ w ; es/ed per head. LDS-staged rows, coalesced in/out ------
template<int H>
__global__ __launch_bounds__(GR, 2)
void gemm_attn_kernel(const float* __restrict__ hin, const float* __restrict__ w,
                      const float* __restrict__ asrc, const float* __restrict__ adst,
                      float* __restrict__ xe, float* __restrict__ es, float* __restrict__ ed) {
    __shared__ float sh[GR * 65];       // +1 pad: (row+c)%32 banks, 2-way free
    int base = blockIdx.x * GR;
    const float4* gin = (const float4*)(hin + (size_t)base * HD);
    for (int i = threadIdx.x; i < GR * (HD / 4); i += GR) {
        float4 v = gin[i];
        int row = i >> 4, q = i & 15;
        sh[row * 65 + 4 * q + 0] = v.x;
        sh[row * 65 + 4 * q + 1] = v.y;
        sh[row * 65 + 4 * q + 2] = v.z;
        sh[row * 65 + 4 * q + 3] = v.w;
    }
    __syncthreads();
    int t = base + threadIdx.x;
    float acc[HD];
    #pragma unroll
    for (int k = 0; k < HD; ++k) acc[k] = 0.f;
    #pragma unroll 1
    for (int c0 = 0; c0 < HD; c0 += 8) {
        float r8[8];
        #pragma unroll
        for (int j = 0; j < 8; ++j) r8[j] = sh[threadIdx.x * 65 + c0 + j];
        #pragma unroll
        for (int j = 0; j < 8; ++j) {
            #pragma unroll
            for (int k = 0; k < HD; ++k)
                acc[k] = fmaf(r8[j], w[(c0 + j) * HD + k], acc[k]);  // uniform -> s_load
        }
    }
    constexpr int C = HD / H;
    float esa[H], eda[H];
    #pragma unroll
    for (int h = 0; h < H; ++h) { esa[h] = 0.f; eda[h] = 0.f; }
    #pragma unroll
    for (int k = 0; k < HD; ++k) {
        esa[k / C] = fmaf(acc[k], asrc[k], esa[k / C]);
        eda[k / C] = fmaf(acc[k], adst[k], eda[k / C]);
    }
    #pragma unroll
    for (int h = 0; h < H; ++h) { es[t * H + h] = esa[h]; ed[t * H + h] = eda[h]; }
    __syncthreads();                    // all compute reads of sh done
    #pragma unroll
    for (int k = 0; k < HD; ++k) sh[threadIdx.x * 65 + k] = acc[k];
    __syncthreads();
    float4* gout = (float4*)(xe + (size_t)base * HD);
    for (int i = threadIdx.x; i < GR * (HD / 4); i += GR) {
        int row = i >> 4, q = i & 15;
        gout[i] = make_float4(sh[row * 65 + 4*q], sh[row * 65 + 4*q + 1],
                              sh[row * 65 + 4*q + 2], sh[row * 65 + 4*q + 3]);
    }
}

// ------- fused aggregation: one wave per (batch,node) ------------------------
// 4 groups x 16 lanes; group owns an edge, lane owns 4 channels (float4).
template<int H, bool DO_ELU>
__global__ __launch_bounds__(256, 8)
void agg_kernel(const float* __restrict__ xe, const float* __restrict__ es,
                const float* __restrict__ ed, const int* __restrict__ cnt,
                const int* __restrict__ perm, const float* __restrict__ bias,
                float* __restrict__ hout) {
    int wid = blockIdx.x * 4 + (threadIdx.x >> 6);
    if (wid >= BN) return;
    int lane  = threadIdx.x & 63;
    int group = lane >> 4;
    int c4    = lane & 15;
    int bb = wid / N, node = wid - bb * N;
    int deg = cnt[node];
    int baseE = node * CAP;
    int h = (H == 8) ? (c4 >> 1) : 0;        // channels 4*c4..+3 lie in one head
    const float*  es_b = es + bb * (N * H);
    const float4* xe4  = (const float4*)(xe + bb * (N * HD));
    float edv = ed[(bb * N + node) * H + h];
    float4 acc = {0.f, 0.f, 0.f, 0.f};
    float ssum = 0.f;
    #pragma unroll 2
    for (int jb = 0; jb < deg; jb += 4) {
        int j = jb + group;
        bool valid = (j < deg);
        int src = perm[baseE + (valid ? j : 0)];     // slot 0 always exists
        float e = es_b[src * H + h] + edv;
        e = fmaxf(e, 0.2f * e);                      // leaky_relu(0.2)
        float p = valid ? __expf(e) : 0.f;
        ssum += p;
        float4 xv = xe4[src * 16 + c4];              // 256B/group gather
        acc.x = fmaf(p, xv.x, acc.x);
        acc.y = fmaf(p, xv.y, acc.y);
        acc.z = fmaf(p, xv.z, acc.z);
        acc.w = fmaf(p, xv.w, acc.w);
    }
    #pragma unroll
    for (int m = 16; m < 64; m <<= 1) {
        acc.x += __shfl_xor(acc.x, m, 64);
        acc.y += __shfl_xor(acc.y, m, 64);
        acc.z += __shfl_xor(acc.z, m, 64);
        acc.w += __shfl_xor(acc.w, m, 64);
        ssum  += __shfl_xor(ssum,  m, 64);
    }
    if (lane < 16) {
        float inv = 1.f / ssum;
        const float4* b4 = (const float4*)bias;
        float4 bv = b4[c4];
        float4 r;
        r.x = acc.x * inv + bv.x;
        r.y = acc.y * inv + bv.y;
        r.z = acc.z * inv + bv.z;
        r.w = acc.w * inv + bv.w;
        if (DO_ELU) {
            r.x = (r.x > 0.f) ? r.x : expm1f(r.x);
            r.y = (r.y > 0.f) ? r.y : expm1f(r.y);
            r.z = (r.z > 0.f) ? r.z : expm1f(r.z);
            r.w = (r.w > 0.f) ? r.w : expm1f(r.w);
        }
        ((float4*)hout)[(bb * N + node) * 16 + c4] = r;
    }
}

// ------- conv1d(k=3) + relu + 64->3 projection; LDS-staged node tile ---------
constexpr int CT = 128;                 // nodes per block
__global__ __launch_bounds__(CT, 2)
void conv_out_kernel(const float* __restrict__ h, const float* __restrict__ cwT,
                     const float* __restrict__ cb, const float* __restrict__ ow,
                     const float* __restrict__ ob, float* __restrict__ out) {
    __shared__ float sh[(CT + 2) * 65];          // +1 pad
    int bb = blockIdx.y;
    int base = blockIdx.x * CT;
    for (int fid = threadIdx.x; fid < (CT + 2) * HD; fid += CT) {
        int row = fid >> 6, c = fid & 63;
        int m = base - 1 + row;
        float v = (m >= 0 && m < N) ? h[((size_t)bb * N + m) * HD + c] : 0.f;
        sh[row * 65 + c] = v;
    }
    __syncthreads();
    int n = base + threadIdx.x;
    if (n >= N) return;
    float acc[HD];
    #pragma unroll
    for (int o = 0; o < HD; ++o) acc[o] = cb[o];          // uniform s_load
    for (int c = 0; c < HD; ++c) {
        float r0 = sh[(threadIdx.x)     * 65 + c];
        float r1 = sh[(threadIdx.x + 1) * 65 + c];
        float r2 = sh[(threadIdx.x + 2) * 65 + c];
        const float* wc = cwT + c * 192;                  // [dt][o], uniform s_loads
        #pragma unroll
        for (int o = 0; o < HD; ++o)
            acc[o] = fmaf(r0, wc[o], fmaf(r1, wc[64 + o], fmaf(r2, wc[128 + o], acc[o])));
    }
    float p0 = ob[0], p1 = ob[1], p2 = ob[2];
    #pragma unroll
    for (int o = 0; o < HD; ++o) {
        float v = fmaxf(acc[o], 0.f);
        p0 = fmaf(v, ow[o * 3 + 0], p0);
        p1 = fmaf(v, ow[o * 3 + 1], p1);
        p2 = fmaf(v, ow[o * 3 + 2], p2);
    }
    out[(size_t)bb * 3 * N + 0 * N + n] = p0;
    out[(size_t)bb * 3 * N + 1 * N + n] = p1;
    out[(size_t)bb * 3 * N + 2 * N + n] = p2;
}

extern "C" void kernel_launch(void* const* d_in, const int* in_sizes, int n_in,
                              void* d_out, int out_size, void* d_ws, size_t ws_size,
                              hipStream_t stream) {
    const float* x      = (const float*)d_in[0];
    const int*   ei     = (const int*)  d_in[1];
    const float* proj_w = (const float*)d_in[2];
    const float* proj_b = (const float*)d_in[3];
    const float* g_w [3] = {(const float*)d_in[4], (const float*)d_in[8],  (const float*)d_in[12]};
    const float* g_as[3] = {(const float*)d_in[5], (const float*)d_in[9],  (const float*)d_in[13]};
    const float* g_ad[3] = {(const float*)d_in[6], (const float*)d_in[10], (const float*)d_in[14]};
    const float* g_b [3] = {(const float*)d_in[7], (const float*)d_in[11], (const float*)d_in[15]};
    const float* conv_w = (const float*)d_in[16];
    const float* conv_b = (const float*)d_in[17];
    const float* out_w  = (const float*)d_in[18];
    const float* out_b  = (const float*)d_in[19];
    float* out = (float*)d_out;

    // workspace layout (fp32 elements)
    float* bufA = (float*)d_ws;                      // BN*HD
    float* bufX = bufA + (size_t)BN * HD;            // BN*HD
    float* es   = bufX + (size_t)BN * HD;            // BN*8 (max H)
    float* ed   = es   + (size_t)BN * 8;             // BN*8
    int* cnt  = (int*)(ed + (size_t)BN * 8);         // N
    int* perm = cnt + N;                             // N*CAP
    float* cwT = (float*)(perm + (size_t)N * CAP);   // 64*64*3

    const int TB = 256;
    const int gE = (EL + TB - 1) / TB;

    // CSR build: memset + single scatter (padded buckets, no scan)
    hipMemsetAsync(cnt, 0, N * sizeof(int), stream);
    scatter_kernel<<<gE, TB, 0, stream>>>(ei, cnt, perm);

    // conv weight transpose
    tw_kernel<<<(HD * HD * 3 + TB - 1) / TB, TB, 0, stream>>>(conv_w, cwT);

    // layer 0: proj + gemm + attn fused (reads x directly)
    fused0_kernel<<<BN / GR, GR, 0, stream>>>(x, proj_w, proj_b, g_w[0], g_as[0], g_ad[0],
                                              bufX, es, ed);
    agg_kernel<8, true><<<BN / 4, TB, 0, stream>>>(bufX, es, ed, cnt, perm, g_b[0], bufA);

    // layer 1 (H=8) + ELU
    gemm_attn_kernel<8><<<BN / GR, GR, 0, stream>>>(bufA, g_w[1], g_as[1], g_ad[1], bufX, es, ed);
    agg_kernel<8, true><<<BN / 4, TB, 0, stream>>>(bufX, es, ed, cnt, perm, g_b[1], bufA);

    // layer 2 (H=1), no ELU
    gemm_attn_kernel<1><<<BN / GR, GR, 0, stream>>>(bufA, g_w[2], g_as[2], g_ad[2], bufX, es, ed);
    agg_kernel<1, false><<<BN / 4, TB, 0, stream>>>(bufX, es, ed, cnt, perm, g_b[2], bufA);

    // conv1d(k=3) + relu + final projection, writes [B,3,N]
    conv_out_kernel<<<dim3((N + CT - 1) / CT, B), CT, 0, stream>>>(bufA, cwT, conv_b, out_w, out_b, out);
}